// Round 8
// baseline (684.099 us; speedup 1.0000x reference)
//
#include <hip/hip_runtime.h>
#include <hip/hip_bf16.h>
#include <math.h>
#include <stdint.h>

// Problem constants
#define N_TOK   8192          // SL*BS
#define HS      1024
#define FFN     4096
#define NE      8
#define NA      16384         // N_TOK * TOPK
#define CAP     16384         // per-expert bucket capacity (worst case)
#define BMT     128           // M-tile rows
#define MAXT    136           // max total M-tiles: 16384/128 + 8
#define PERMSZ  16777216ULL   // NA * HS floats

typedef __attribute__((ext_vector_type(8))) short          bf16x8;
typedef __attribute__((ext_vector_type(4))) float          f32x4;
typedef __attribute__((ext_vector_type(4))) float          fvec4;
typedef __attribute__((ext_vector_type(4))) unsigned short usvec4;

__device__ __forceinline__ void gl_lds16(const void* g, void* l) {
  __builtin_amdgcn_global_load_lds(
      (const __attribute__((address_space(1))) unsigned int*)g,
      (__attribute__((address_space(3))) unsigned int*)l,
      16, 0, 0);
}

__device__ __forceinline__ unsigned short f2bf(float f) {
  union { float f; unsigned int u; } v; v.f = f;
  unsigned int r = v.u + 0x7FFFu + ((v.u >> 16) & 1u);
  return (unsigned short)(r >> 16);
}

// ---------------- conversion kernels ----------------

__global__ void cvt_x_kernel(const fvec4* __restrict__ in, unsigned short* __restrict__ out, int n4) {
  int i = blockIdx.x * 256 + threadIdx.x;
  if (i >= n4) return;
  fvec4 v = in[i];
  usvec4 o;
  o[0] = f2bf(v[0]); o[1] = f2bf(v[1]); o[2] = f2bf(v[2]); o[3] = f2bf(v[3]);
  *(usvec4*)(out + (size_t)i * 4) = o;
}

// in [E][R][C] f32 -> out [E][C][R] bf16 (K-contiguous B^T layout for GEMM)
__global__ void tpose_cvt_kernel(const float* __restrict__ in, unsigned short* __restrict__ out,
                                 int R, int C) {
  __shared__ float t[64][65];
  int bc = blockIdx.x * 64, br = blockIdx.y * 64, e = blockIdx.z;
  const float* ine = in + (size_t)e * R * C;
  unsigned short* oute = out + (size_t)e * R * C;
  int tx = threadIdx.x & 63, ty = threadIdx.x >> 6;   // ty in [0,4)
#pragma unroll
  for (int q = 0; q < 16; ++q) {
    int r = ty * 16 + q;
    t[r][tx] = ine[(size_t)(br + r) * C + bc + tx];
  }
  __syncthreads();
#pragma unroll
  for (int q = 0; q < 16; ++q) {
    int c = ty * 16 + q;
    oute[(size_t)(bc + c) * R + br + tx] = f2bf(t[tx][c]);
  }
}

// ---------------- routing ----------------

__global__ void route_kernel(const int* __restrict__ idx, const float* __restrict__ wts,
                             int* __restrict__ counts, int* __restrict__ btok,
                             int* __restrict__ bslot, float* __restrict__ bw) {
  int a = blockIdx.x * 256 + threadIdx.x;
  if (a >= NA) return;
  int e = idx[a];
  int pos = atomicAdd(&counts[e], 1);
  btok[(size_t)e * CAP + pos]  = a >> 1;     // token id
  bslot[(size_t)e * CAP + pos] = a;          // destination slot in perm buffer
  bw[(size_t)e * CAP + pos]    = wts[a];
}

__global__ void build_tiles_kernel(int* __restrict__ counts, int2* __restrict__ table) {
  if (threadIdx.x == 0 && blockIdx.x == 0) {
    int nt = 0;
    for (int e = 0; e < NE; ++e) {
      int c = counts[e];
      int t = (c + BMT - 1) >> 7;
      for (int m = 0; m < t && nt < MAXT; ++m) table[nt++] = make_int2(e, m);
    }
    counts[8] = nt;
  }
}

// ---- grouped GEMM: persistent work-stealing, 128x128 tile, BK=32, 4 waves ----
// Per-wave 64x64 (acc[4][4] = 64 AGPR, ~125 regs total -> 3 blocks/CU, 12 waves/CU).
// m97 loop: stage T+1 (4 gl_lds) -> 8 ds_read_b128 -> 16 MFMA -> vmcnt(0) -> barrier.
// Swizzle (proven 0-conflict): kbyte ^= ((row>>1)&3)<<4, both staging source and reads.
// Units pulled col-major off an atomic counter: B-slice stays L2-resident, zero tail.
template <int EPI, int AROW, int KTOT, int NU>
__global__ __launch_bounds__(256, 3)
void moe_gemm(const unsigned short* __restrict__ Ab,   // xb (EPI=0) or h (EPI=1)
              const unsigned short* __restrict__ Bb,   // w1T / w2T, [E][N][K] bf16
              unsigned short* __restrict__ hout,       // EPI=0 output
              float* __restrict__ perm,                // EPI=1 output (2 K-half buffers)
              const int* __restrict__ btok,
              const int* __restrict__ bslot,
              const float* __restrict__ bw,
              const int* __restrict__ counts,
              const int2* __restrict__ table,
              int* __restrict__ ctr, int p0, int tc) {
  constexpr int NT = KTOT / 32;
  __shared__ char lds[32768];
  __shared__ int s_u;

  int tid = threadIdx.x;
  int wid = tid >> 6, lane = tid & 63;
  int wm = wid >> 1, wn = wid & 1;
  int nt = counts[8];

  // unit-invariant staging geometry: 16 chunks of 1KB (16 rows x 64B), 4 per wave
  int rin = lane >> 2;                                  // row-in-chunk 0..15
  int klog = ((lane & 3) * 16) ^ (((rin >> 1) & 3) << 4);
  int dst[4];
#pragma unroll
  for (int q = 0; q < 4; ++q) dst[q] = (wid * 4 + q) * 1024;

  // fragment read offsets (swizzle is lane-constant: rows differ by multiples of 16)
  int l15 = lane & 15, l16 = lane >> 4;
  int swzr = ((l15 >> 1) & 3) << 4;
  int ks = l16 * 16;
  int offA0 = (wm * 64 + l15) * 64 + (ks ^ swzr);
  int offB0 = 8192 + (wn * 64 + l15) * 64 + (ks ^ swzr);

  for (;;) {
    __syncthreads();                      // LDS + s_u safe for reuse
    if (tid == 0) s_u = atomicAdd(ctr, 1);
    __syncthreads();
    int u = s_u;
    if (u >= NU) return;

    // decode unit (col-major within a K-half for L2 locality of the B slice)
    int kq, col, j;
    if (EPI == 0) { kq = 0; col = u / MAXT; j = u % MAXT; }
    else          { kq = u / (8 * MAXT); int rem = u % (8 * MAXT); col = rem / MAXT; j = rem % MAXT; }
    if (j >= nt || j < p0 || j >= p0 + tc) continue;
    int2 te = table[j];
    int e = te.x, tm = te.y;
    int count = counts[e];
    int slotb = j - p0;
    int bn0 = col * 128;
    int kbyte0 = kq * (KTOT * 2);

    const unsigned short* Be = Bb + (size_t)e * ((size_t)FFN * HS);

    const char* src[4];
#pragma unroll
    for (int q = 0; q < 4; ++q) {
      int c = wid * 4 + q;
      if (c < 8) {          // A rows c*16 + rin
        int row = c * 16 + rin;
        if (EPI == 0) {
          int grow = tm * BMT + row;
          int tok = (grow < count) ? btok[(size_t)e * CAP + grow] : 0;
          src[q] = (const char*)(Ab + (size_t)tok * AROW) + kbyte0 + klog;
        } else {
          src[q] = (const char*)(Ab + ((size_t)slotb * BMT + row) * AROW) + kbyte0 + klog;
        }
      } else {              // B rows bn0 + (c-8)*16 + rin
        int nrow = bn0 + (c - 8) * 16 + rin;
        src[q] = (const char*)(Be + (size_t)nrow * AROW) + kbyte0 + klog;
      }
    }

    f32x4 acc[4][4] = {};

    // prologue: stage K-tile 0 -> buf 0
#pragma unroll
    for (int q = 0; q < 4; ++q) gl_lds16(src[q], lds + dst[q]);
    asm volatile("s_waitcnt vmcnt(0)" ::: "memory");
    __builtin_amdgcn_s_barrier();
    __builtin_amdgcn_sched_barrier(0);

    for (int t = 0; t < NT; ++t) {
      const char* rbuf = lds + (t & 1) * 16384;
      char* db = lds + ((t + 1) & 1) * 16384;
      if (t + 1 < NT) {
#pragma unroll
        for (int q = 0; q < 4; ++q)
          gl_lds16(src[q] + (size_t)(t + 1) * 64, db + dst[q]);
      }
      bf16x8 a[4], b[4];
#pragma unroll
      for (int n = 0; n < 4; ++n) b[n] = *(const bf16x8*)(rbuf + offB0 + n * 1024);
#pragma unroll
      for (int i = 0; i < 4; ++i) a[i] = *(const bf16x8*)(rbuf + offA0 + i * 1024);
      __builtin_amdgcn_s_setprio(1);
#pragma unroll
      for (int i = 0; i < 4; ++i)
#pragma unroll
        for (int n = 0; n < 4; ++n)
          acc[i][n] = __builtin_amdgcn_mfma_f32_16x16x32_bf16(a[i], b[n], acc[i][n], 0, 0, 0);
      __builtin_amdgcn_s_setprio(0);
      __builtin_amdgcn_sched_barrier(0);
      asm volatile("s_waitcnt vmcnt(0)" ::: "memory");
      __builtin_amdgcn_s_barrier();
      __builtin_amdgcn_sched_barrier(0);
    }

    // epilogue: per-wave LDS repack (8KB region) -> vector global stores
    char* wlds = lds + wid * 8192;        // 32 rows x 256B (64 f32)
#pragma unroll
    for (int p = 0; p < 2; ++p) {
#pragma unroll
      for (int ii = 0; ii < 2; ++ii) {
        int i = p * 2 + ii;
#pragma unroll
        for (int n = 0; n < 4; ++n) {
          int waddr = (ii * 16 + l16 * 4) * 256 + (n * 16 + l15) * 4;
#pragma unroll
          for (int rr = 0; rr < 4; ++rr)
            *(float*)(wlds + waddr + rr * 256) = acc[i][n][rr];
        }
      }
      asm volatile("s_waitcnt lgkmcnt(0)" ::: "memory");
      __builtin_amdgcn_sched_barrier(0);
#pragma unroll
      for (int rd = 0; rd < 8; ++rd) {
        int row = rd * 4 + l16;            // 0..31
        f32x4 v = *(const f32x4*)(wlds + row * 256 + l15 * 16);
        int colg = bn0 + wn * 64 + l15 * 4;
        if (EPI == 0) {
          usvec4 o;
#pragma unroll
          for (int z = 0; z < 4; ++z) {
            float vv = v[z];
            float x2 = vv * vv;
            float u2 = 1.5957691216057308f * vv * fmaf(0.044715f, x2, 1.0f);
            u2 = fminf(fmaxf(u2, -30.f), 30.f);
            float ee = __expf(u2);
            o[z] = f2bf(vv * __fdividef(ee, ee + 1.0f));
          }
          size_t hrow = (size_t)slotb * BMT + wm * 64 + p * 32 + row;
          *(usvec4*)(hout + hrow * FFN + colg) = o;
        } else {
          int grow = tm * BMT + wm * 64 + p * 32 + row;
          if (grow < count) {
            int s = bslot[(size_t)e * CAP + grow];
            float wgt = bw[(size_t)e * CAP + grow];
            fvec4 o;
#pragma unroll
            for (int z = 0; z < 4; ++z) o[z] = wgt * v[z];
            *(fvec4*)(perm + (size_t)kq * PERMSZ + (size_t)s * HS + colg) = o;
          }
        }
      }
      __builtin_amdgcn_sched_barrier(0);
    }
  }
}

// ---------------- combine: out[t] = sum over 2 slots x 2 K-halves ----------------
__global__ void combine_kernel(const fvec4* __restrict__ perm, fvec4* __restrict__ out, int n4) {
  int i = blockIdx.x * 256 + threadIdx.x;
  if (i >= n4) return;
  int t = i >> 8;            // HS/4 = 256 fvec4 per row
  int c = i & 255;
  const fvec4* p0 = perm;
  const fvec4* p1 = perm + PERMSZ / 4;
  size_t r0 = (size_t)(2 * t) * 256 + c;
  size_t r1 = (size_t)(2 * t + 1) * 256 + c;
  out[i] = (p0[r0] + p1[r0]) + (p0[r1] + p1[r1]);
}

// ---------------- host ----------------

extern "C" void kernel_launch(void* const* d_in, const int* in_sizes, int n_in,
                              void* d_out, int out_size, void* d_ws, size_t ws_size,
                              hipStream_t stream) {
  const float* x   = (const float*)d_in[0];
  const float* ew  = (const float*)d_in[1];
  // d_in[2] = scores (unused by reference output)
  const float* w1  = (const float*)d_in[3];
  const float* w2  = (const float*)d_in[4];
  const int*   eix = (const int*)d_in[5];

  char* ws = (char*)d_ws;
  const size_t o_w1T    = 0;                       // 67,108,864
  const size_t o_w2T    = 67108864ULL;             // 67,108,864
  const size_t o_xb     = 134217728ULL;            // 16,777,216
  const size_t o_btok   = 150994944ULL;            // 524,288
  const size_t o_bslot  = 151519232ULL;            // 524,288
  const size_t o_bw     = 152043520ULL;            // 524,288
  const size_t o_counts = 152567808ULL;            // 256
  const size_t o_table  = 152568064ULL;            // 2,048
  const size_t o_ctr    = 152570112ULL;            // 2,048 (256 counters)
  const size_t o_perm   = 152572160ULL;            // 2 x 67,108,864
  const size_t o_h      = 286789888ULL;            // up to 142,606,336

  unsigned short* w1T = (unsigned short*)(ws + o_w1T);
  unsigned short* w2T = (unsigned short*)(ws + o_w2T);
  unsigned short* xb  = (unsigned short*)(ws + o_xb);
  int*   btok   = (int*)(ws + o_btok);
  int*   bslot  = (int*)(ws + o_bslot);
  float* bw     = (float*)(ws + o_bw);
  int*   counts = (int*)(ws + o_counts);
  int2*  table  = (int2*)(ws + o_table);
  int*   ctrs   = (int*)(ws + o_ctr);
  float* perm   = (float*)(ws + o_perm);
  unsigned short* hbuf = (unsigned short*)(ws + o_h);

  // h-buffer chunking if workspace is small
  long long havail = (long long)ws_size - (long long)o_h;
  long long tile_bytes = (long long)BMT * FFN * 2;   // 1 MB per M-tile
  int tc = (int)(havail / tile_bytes);
  if (tc < 1) tc = 1;
  if (tc > MAXT) tc = MAXT;
  int npass = (MAXT + tc - 1) / tc;
  if (npass > 128) npass = 128;

  hipMemsetAsync(counts, 0, 256, stream);
  hipMemsetAsync(ctrs, 0, 2048, stream);

  cvt_x_kernel<<<(N_TOK * HS / 4 + 255) / 256, 256, 0, stream>>>(
      (const fvec4*)x, xb, N_TOK * HS / 4);
  tpose_cvt_kernel<<<dim3(FFN / 64, HS / 64, NE), 256, 0, stream>>>(w1, w1T, HS, FFN);
  tpose_cvt_kernel<<<dim3(HS / 64, FFN / 64, NE), 256, 0, stream>>>(w2, w2T, FFN, HS);

  route_kernel<<<(NA + 255) / 256, 256, 0, stream>>>(eix, ew, counts, btok, bslot, bw);
  build_tiles_kernel<<<1, 64, 0, stream>>>(counts, table);

  for (int p = 0; p < npass; ++p) {
    // GEMM1: units = 32 cols x 136 tiles = 4352, K=1024
    moe_gemm<0, HS, HS, 32 * MAXT><<<dim3(1024), 256, 0, stream>>>(
        xb, w1T, hbuf, perm, btok, bslot, bw, counts, table,
        &ctrs[p * 2 + 0], p * tc, tc);
    // GEMM2: units = 2 K-halves x 8 cols x 136 tiles = 2176, K=2048 each
    moe_gemm<1, FFN, FFN / 2, 2 * 8 * MAXT><<<dim3(1024), 256, 0, stream>>>(
        hbuf, w2T, hbuf, perm, btok, bslot, bw, counts, table,
        &ctrs[p * 2 + 1], p * tc, tc);
  }

  combine_kernel<<<(N_TOK * HS / 4 + 255) / 256, 256, 0, stream>>>(
      (const fvec4*)perm, (fvec4*)d_out, N_TOK * HS / 4);
}